// Round 13
// baseline (304.586 us; speedup 1.0000x reference)
//
#include <hip/hip_runtime.h>
#include <hip/hip_bf16.h>

// FeedForwardQuantum: out = relu( (cos(theta)*cos(x@Wmap^T)) @ W1^T + b1 ) @ W2^T + b2
// ALL tensors fp32. Compute path: fp32 -> bf16 MFMA -> fp32 out.
//  kPre: merged pre-pass (blocks [0,768): W2->bf16 swizzled; [768,780): W1+b1 pack;
//        [780,1804): q = cos(th)*cos(x@Wmap^T) -> qp bf16 [16384][32] swizzled).
//  kG  : r12's h-ahead pipeline (h(t+1) computed in registers during main(t); the
//        inter-barrier gap is only 4x ds_write_b64) with the crash mechanism
//        REMOVED: all register loads are plain C++ derefs (compiler-visible VMEM
//        -> correct waitcnt even under spills). r6/r8/r12 crashes were opaque
//        inline-asm loads + compiler VMEM miscounting. Manual waits: full drains
//        only (vmcnt(0) pre-B1, lgkmcnt(0) pre-B2) + sched_barrier fences.

typedef __attribute__((ext_vector_type(4))) float f32x4;
typedef __attribute__((ext_vector_type(8))) short bf16x8;

#define F_TOTAL 16384
#define E_DIM   768
#define FFN     3072

static __device__ __forceinline__ unsigned short f2bf(float f) {
    union { float f; unsigned int i; } v; v.f = f;
    unsigned int r = v.i + 0x7FFFu + ((v.i >> 16) & 1u);   // RNE
    return (unsigned short)(r >> 16);
}
static __device__ __forceinline__ unsigned int pkbf(float a, float b) {
    __hip_bfloat162 h2 = __float22bfloat162_rn(float2{a, b});   // a -> low, b -> high
    union { __hip_bfloat162 h; unsigned int u; } v; v.h = h2; return v.u;
}
static __device__ __forceinline__ void gload16(const void* g, void* l) {
    __builtin_amdgcn_global_load_lds((const __attribute__((address_space(1))) unsigned int*)g,
                                     (__attribute__((address_space(3))) unsigned int*)l,
                                     16, 0, 0);
}

// ---------------- kPre: merged W2-convert / W1-pack / q-compute ---------------
__global__ __launch_bounds__(256) void kPre(const float* __restrict__ x,
                                            const float* __restrict__ wm,
                                            const float* __restrict__ th,
                                            const float* __restrict__ w1,
                                            const float* __restrict__ b1,
                                            const float* __restrict__ w2,
                                            unsigned short* __restrict__ w2b,
                                            unsigned short* __restrict__ w1p,
                                            unsigned short* __restrict__ qp) {
    __shared__ float wms[10 * 768];  // 30 KB (q role only)
    const int bid = (int)blockIdx.x;
    const int tid = (int)threadIdx.x;

    if (bid < 768) {
        const int n = bid;
#pragma unroll
        for (int c0 = 0; c0 < 2; ++c0) {
            int c = tid + c0 * 256;
            if (c < 384) {
                const float4* src = (const float4*)(w2 + (size_t)n * FFN + c * 8);
                float4 a = src[0], b = src[1];
                bf16x8 v;
                v[0] = (short)f2bf(a.x); v[1] = (short)f2bf(a.y);
                v[2] = (short)f2bf(a.z); v[3] = (short)f2bf(a.w);
                v[4] = (short)f2bf(b.x); v[5] = (short)f2bf(b.y);
                v[6] = (short)f2bf(b.z); v[7] = (short)f2bf(b.w);
                *(bf16x8*)(w2b + (size_t)n * FFN + (size_t)(c ^ (n & 7)) * 8) = v;
            }
        }
        return;
    }
    if (bid < 780) {
        int k = (bid - 768) * 256 + tid;
        if (k < FFN) {
            float r[32];
#pragma unroll
            for (int w = 0; w < 10; ++w) r[w] = w1[k * 10 + w];
            r[10] = b1[k];
#pragma unroll
            for (int w = 11; w < 32; ++w) r[w] = 0.f;
#pragma unroll
            for (int c = 0; c < 4; ++c) {
                bf16x8 v;
#pragma unroll
                for (int e = 0; e < 8; ++e) v[e] = (short)f2bf(r[c * 8 + e]);
                *(bf16x8*)(w1p + (size_t)k * 32 + (size_t)((c ^ (k & 3)) * 8)) = v;
            }
        }
        return;
    }

    for (int i = tid; i < 10 * 768; i += 256) wms[i] = wm[i];
    __syncthreads();

    const int wv = tid >> 6, l = tid & 63;
    const int mbase = (bid - 780) * 16 + wv * 4;
    const float thv = (l < 10) ? th[l] : 0.f;
    const float cth = __cosf(thv);

#pragma unroll
    for (int r = 0; r < 4; ++r) {
        const int m = mbase + r;
        const float4* xp = (const float4*)(x + (size_t)m * E_DIM);
        const float4 xa = xp[l], xb = xp[64 + l], xc = xp[128 + l];
        float s[10];
#pragma unroll
        for (int w = 0; w < 10; ++w) {
            const float4* wp = (const float4*)(wms + w * E_DIM);
            const float4 wa = wp[l], wb = wp[64 + l], wc = wp[128 + l];
            float t0 = xa.x * wa.x;
            float t1 = xa.y * wa.y;
            t0 = fmaf(xa.z, wa.z, t0); t1 = fmaf(xa.w, wa.w, t1);
            t0 = fmaf(xb.x, wb.x, t0); t1 = fmaf(xb.y, wb.y, t1);
            t0 = fmaf(xb.z, wb.z, t0); t1 = fmaf(xb.w, wb.w, t1);
            t0 = fmaf(xc.x, wc.x, t0); t1 = fmaf(xc.y, wc.y, t1);
            t0 = fmaf(xc.z, wc.z, t0); t1 = fmaf(xc.w, wc.w, t1);
            s[w] = t0 + t1;
        }
#pragma unroll
        for (int w = 0; w < 10; ++w) {
            float v = s[w];
            v += __shfl_xor(v, 1);  v += __shfl_xor(v, 2);  v += __shfl_xor(v, 4);
            v += __shfl_xor(v, 8);  v += __shfl_xor(v, 16); v += __shfl_xor(v, 32);
            s[w] = v;
        }
        if (l < 32) {
            float sv = 0.f;
#pragma unroll
            for (int w = 0; w < 10; ++w) sv = (l == w) ? s[w] : sv;
            float val = (l < 10) ? (cth * __cosf(sv)) : ((l == 10) ? 1.0f : 0.f);
            qp[(size_t)m * 32 + (size_t)((((l >> 3) ^ (m & 3)) * 8) + (l & 7))] = f2bf(val);
        }
    }
}

// ---------------- kG: h-ahead pipelined fused GEMM (compiler-visible loads) ---
// 512 blocks (128 m-tiles x 4 n-slabs), 512 threads (8 waves, 2m x 4n).
// BM=128, BN=192, BK=64. LDS = 2x24K (w2 dbuf) + 16K (hs) = 64 KiB -> 2 blocks/CU.
// Step T: [vmcnt0; B1] -> STAGE(T+1) -> write hs <- hp (4 ds_write_b64) ->
//   load W1(T+2) -> [lgkm0; B2] -> { hp = h(T+1) (4 MFMA + relu/pack, reg-only)
//   overlapped with main(T): 14 ds_read_b128 + 24 MFMA }.
__global__ __launch_bounds__(512, 4) void kG(const unsigned short* __restrict__ w2b,
                                             const float* __restrict__ b2,
                                             const unsigned short* __restrict__ qp,
                                             const unsigned short* __restrict__ w1p,
                                             float* __restrict__ outp) {
    __shared__ __align__(16) unsigned short w2s[2][192 * 64];  // 48 KB, [n][k] swz8
    __shared__ __align__(16) unsigned short hs[128 * 64];      // 16 KB, [m][k] swz8

    const int tid = (int)threadIdx.x;
    const int wv = tid >> 6, l = tid & 63;
    const int bid = (int)blockIdx.x;
    const int x8 = bid & 7, yb = bid >> 3;          // 2 XCDs per n-slab
    const int m0 = ((x8 & 1) * 64 + yb) * 128;
    const int n0 = (x8 >> 1) * 192;

    const int rw = tid >> 3, cw = tid & 7;   // W2 staging row/chunk
    const int wr = wv >> 2, wc = wv & 3;     // main-phase wave tile (2m x 4n)
    const int par = wv & 1;                  // window-order parity

    // h-write element offsets (swapped layout): lane l holds h[hm][ki*16+(l>>4)*4..+3]
    int hwo[4];
    {
        const int hm = wv * 16 + (l & 15);
        const int kb = (l >> 4) * 4;
#pragma unroll
        for (int ki = 0; ki < 4; ++ki) {
            int k = ki * 16 + kb;
            int c = k >> 3;
            hwo[ki] = hm * 64 + ((c ^ (hm & 7)) * 8) + (k & 7);
        }
    }

    const unsigned short* p1 = w1p + (l & 15) * 32 + ((l >> 4) ^ (l & 3)) * 8;

#define STAGE(BUF, KT) do { int k0_ = (KT) * 64;                                   \
    _Pragma("unroll") for (int i_ = 0; i_ < 3; ++i_) {                             \
        int r_ = i_ * 64 + rw;                                                     \
        gload16(w2b + (size_t)(n0 + r_) * FFN + k0_ + (size_t)cw * 8,              \
                (unsigned short*)w2s[BUF] + i_ * 4096 + wv * 512); } } while (0)

    // plain C++ W1 fragment loads (compiler-visible VMEM)
#define LOADW1C(D0, D1, D2, D3, KT) do {                                           \
    const unsigned short* pn_ = p1 + (size_t)(KT) * 2048;                          \
    D0 = *(const bf16x8*)(pn_);                                                    \
    D1 = *(const bf16x8*)(pn_ + 512);                                              \
    D2 = *(const bf16x8*)(pn_ + 1024);                                             \
    D3 = *(const bf16x8*)(pn_ + 1536);                                             \
} while (0)

    // h(t) compute into packed regs hp0..hp3 (reg-only; no LDS)
#define HCOMP(W0, W1_, W2_, W3_) do {                                              \
    f32x4 hv_;                                                                     \
    hv_ = __builtin_amdgcn_mfma_f32_16x16x32_bf16(W0, aq, z4, 0, 0, 0);            \
    hp0.x = pkbf(fmaxf(hv_[0],0.f), fmaxf(hv_[1],0.f));                            \
    hp0.y = pkbf(fmaxf(hv_[2],0.f), fmaxf(hv_[3],0.f));                            \
    hv_ = __builtin_amdgcn_mfma_f32_16x16x32_bf16(W1_, aq, z4, 0, 0, 0);           \
    hp1.x = pkbf(fmaxf(hv_[0],0.f), fmaxf(hv_[1],0.f));                            \
    hp1.y = pkbf(fmaxf(hv_[2],0.f), fmaxf(hv_[3],0.f));                            \
    hv_ = __builtin_amdgcn_mfma_f32_16x16x32_bf16(W2_, aq, z4, 0, 0, 0);           \
    hp2.x = pkbf(fmaxf(hv_[0],0.f), fmaxf(hv_[1],0.f));                            \
    hp2.y = pkbf(fmaxf(hv_[2],0.f), fmaxf(hv_[3],0.f));                            \
    hv_ = __builtin_amdgcn_mfma_f32_16x16x32_bf16(W3_, aq, z4, 0, 0, 0);           \
    hp3.x = pkbf(fmaxf(hv_[0],0.f), fmaxf(hv_[1],0.f));                            \
    hp3.y = pkbf(fmaxf(hv_[2],0.f), fmaxf(hv_[3],0.f));                            \
} while (0)

    // main phase for step T reading hs + w2s[BUF]
#define MAINPH(BUF) do {                                                           \
    const unsigned short* w2c = (const unsigned short*)w2s[BUF];                   \
    _Pragma("unroll")                                                              \
    for (int kx = 0; kx < 2; ++kx) {                                               \
        const int win = kx ^ par;                                                  \
        const int kc = win * 4 + (l >> 4);                                         \
        bf16x8 af[4], bfr[3];                                                      \
        _Pragma("unroll")                                                          \
        for (int mi = 0; mi < 4; ++mi) {                                           \
            int m_ = wr * 64 + mi * 16 + (l & 15);                                 \
            af[mi] = *(const bf16x8*)(hs + m_ * 64 + ((kc ^ (m_ & 7)) * 8));       \
        }                                                                          \
        _Pragma("unroll")                                                          \
        for (int ni = 0; ni < 3; ++ni) {                                           \
            int n_ = wc * 48 + ni * 16 + (l & 15);                                 \
            bfr[ni] = *(const bf16x8*)(w2c + n_ * 64 + ((kc ^ (n_ & 7)) * 8));     \
        }                                                                          \
        __builtin_amdgcn_s_setprio(1);                                             \
        _Pragma("unroll")                                                          \
        for (int ni = 0; ni < 3; ++ni)                                             \
            _Pragma("unroll")                                                      \
            for (int mi = 0; mi < 4; ++mi)                                         \
                acc[mi][ni] = __builtin_amdgcn_mfma_f32_16x16x32_bf16(             \
                    af[mi], bfr[ni], acc[mi][ni], 0, 0, 0);                        \
        __builtin_amdgcn_s_setprio(0);                                             \
    }                                                                              \
} while (0)

    // Step T: write hs from hp (h(T)), then compute hp = h(T+1) during main(T).
#define KSTEP(T, BUF, C0, C1, C2, C3, N0, N1, N2, N3) do {                         \
    asm volatile("s_waitcnt vmcnt(0)" ::: "memory");                               \
    __builtin_amdgcn_sched_barrier(0);                                             \
    __builtin_amdgcn_s_barrier();                                                  \
    __builtin_amdgcn_sched_barrier(0);                                             \
    if ((T) < 47) STAGE((BUF) ^ 1, (T) + 1);                                       \
    *(uint2*)(hs + hwo[0]) = hp0;                                                  \
    *(uint2*)(hs + hwo[1]) = hp1;                                                  \
    *(uint2*)(hs + hwo[2]) = hp2;                                                  \
    *(uint2*)(hs + hwo[3]) = hp3;                                                  \
    if ((T) < 46) LOADW1C(N0, N1, N2, N3, (T) + 2);                                \
    asm volatile("s_waitcnt lgkmcnt(0)" ::: "memory");                             \
    __builtin_amdgcn_sched_barrier(0);                                             \
    __builtin_amdgcn_s_barrier();                                                  \
    __builtin_amdgcn_sched_barrier(0);                                             \
    if ((T) < 47) HCOMP(C0, C1, C2, C3);                                           \
    MAINPH(BUF);                                                                   \
} while (0)

    // ---- prologue: aq + stage(0) + W1(0) -> h(0); then W1(1) in flight ----
    bf16x8 aq = *(const bf16x8*)(qp + (size_t)(m0 + wv * 16 + (l & 15)) * 32
                                    + (size_t)(((l >> 4) ^ (l & 3)) * 8));
    bf16x8 f0, f1, f2, f3, g0, g1, g2, g3;
    const f32x4 z4 = {0.f, 0.f, 0.f, 0.f};
    uint2 hp0, hp1, hp2, hp3;

    STAGE(0, 0);
    LOADW1C(f0, f1, f2, f3, 0);
    HCOMP(f0, f1, f2, f3);                 // hp = h(0); compiler waits on aq/f itself
    LOADW1C(g0, g1, g2, g3, 1);

    f32x4 acc[4][3];
#pragma unroll
    for (int a = 0; a < 4; ++a)
#pragma unroll
        for (int b = 0; b < 3; ++b) acc[a][b] = z4;

#pragma unroll 1
    for (int tt = 0; tt < 24; ++tt) {
        KSTEP(2 * tt,     0, g0, g1, g2, g3, f0, f1, f2, f3);  // h(T+1) from g=W1(T+1)
        KSTEP(2 * tt + 1, 1, f0, f1, f2, f3, g0, g1, g2, g3);  // h(T+1) from f=W1(T+1)
    }
#undef KSTEP
#undef MAINPH
#undef HCOMP
#undef LOADW1C
#undef STAGE

    // epilogue: + b2, fp32 store
#pragma unroll
    for (int ni = 0; ni < 3; ++ni) {
        int n = n0 + wc * 48 + ni * 16 + (l & 15);
        float b2v = b2[n];
#pragma unroll
        for (int mi = 0; mi < 4; ++mi) {
            int mb = m0 + wr * 64 + mi * 16 + (l >> 4) * 4;
#pragma unroll
            for (int jj = 0; jj < 4; ++jj)
                outp[(size_t)(mb + jj) * E_DIM + n] = acc[mi][ni][jj] + b2v;
        }
    }
}

extern "C" void kernel_launch(void* const* d_in, const int* in_sizes, int n_in,
                              void* d_out, int out_size, void* d_ws, size_t ws_size,
                              hipStream_t stream) {
    const float* x    = (const float*)d_in[0];
    const float* wmap = (const float*)d_in[1];
    const float* th   = (const float*)d_in[2];
    const float* w1   = (const float*)d_in[3];
    const float* b1   = (const float*)d_in[4];
    const float* w2   = (const float*)d_in[5];
    const float* b2   = (const float*)d_in[6];
    float* out = (float*)d_out;

    unsigned short* qp  = (unsigned short*)d_ws;            // 16384*32 bf16 = 1 MiB
    unsigned short* w1p = qp + (size_t)F_TOTAL * 32;        // 3072*32 bf16 = 192 KiB
    unsigned short* w2b = w1p + (size_t)FFN * 32;           // 768*3072 bf16 = 4.5 MiB

    kPre<<<1804, 256, 0, stream>>>(x, wmap, th, w1, b1, w2, w2b, w1p, qp);
    kG<<<512, 512, 0, stream>>>(w2b, b2, qp, w1p, out);
}

// Round 14
// 121.016 us; speedup vs baseline: 2.5169x; 2.5169x over previous
//
#include <hip/hip_runtime.h>
#include <hip/hip_bf16.h>

// FeedForwardQuantum: out = relu( (cos(theta)*cos(x@Wmap^T)) @ W1^T + b1 ) @ W2^T + b2
// ALL tensors fp32. Compute path: fp32 -> bf16 MFMA -> fp32 out.
//  kPre: merged pre-pass (blocks [0,768): W2->bf16 swizzled; [768,780): W1+b1 pack;
//        [780,1804): q -> qp bf16 [16384][32] swizzled).
//  kG  : h-ahead with DOUBLE-BUFFERED hs (h(t+1) written straight to hs[(t+1)&1]
//        during main(t) -- no persistent hp regs, single W1 f-set): the r13 spill
//        (FETCH 463MB scratch) is eliminated by cutting ~24 live VGPRs. LDS
//        80 KB = 2x24K w2s + 2x16K hs -> 2 blocks/CU. All VMEM loads are plain
//        C++ derefs (compiler-correct waitcnt under spills); manual waits are
//        full drains only (vmcnt(0) pre-B1 / lgkmcnt(0) pre-B2).

typedef __attribute__((ext_vector_type(4))) float f32x4;
typedef __attribute__((ext_vector_type(8))) short bf16x8;

#define F_TOTAL 16384
#define E_DIM   768
#define FFN     3072

static __device__ __forceinline__ unsigned short f2bf(float f) {
    union { float f; unsigned int i; } v; v.f = f;
    unsigned int r = v.i + 0x7FFFu + ((v.i >> 16) & 1u);   // RNE
    return (unsigned short)(r >> 16);
}
static __device__ __forceinline__ unsigned int pkbf(float a, float b) {
    __hip_bfloat162 h2 = __float22bfloat162_rn(float2{a, b});   // a -> low, b -> high
    union { __hip_bfloat162 h; unsigned int u; } v; v.h = h2; return v.u;
}
static __device__ __forceinline__ void gload16(const void* g, void* l) {
    __builtin_amdgcn_global_load_lds((const __attribute__((address_space(1))) unsigned int*)g,
                                     (__attribute__((address_space(3))) unsigned int*)l,
                                     16, 0, 0);
}

// ---------------- kPre: merged W2-convert / W1-pack / q-compute ---------------
__global__ __launch_bounds__(256) void kPre(const float* __restrict__ x,
                                            const float* __restrict__ wm,
                                            const float* __restrict__ th,
                                            const float* __restrict__ w1,
                                            const float* __restrict__ b1,
                                            const float* __restrict__ w2,
                                            unsigned short* __restrict__ w2b,
                                            unsigned short* __restrict__ w1p,
                                            unsigned short* __restrict__ qp) {
    __shared__ float wms[10 * 768];  // 30 KB (q role only)
    const int bid = (int)blockIdx.x;
    const int tid = (int)threadIdx.x;

    if (bid < 768) {
        const int n = bid;
#pragma unroll
        for (int c0 = 0; c0 < 2; ++c0) {
            int c = tid + c0 * 256;
            if (c < 384) {
                const float4* src = (const float4*)(w2 + (size_t)n * FFN + c * 8);
                float4 a = src[0], b = src[1];
                bf16x8 v;
                v[0] = (short)f2bf(a.x); v[1] = (short)f2bf(a.y);
                v[2] = (short)f2bf(a.z); v[3] = (short)f2bf(a.w);
                v[4] = (short)f2bf(b.x); v[5] = (short)f2bf(b.y);
                v[6] = (short)f2bf(b.z); v[7] = (short)f2bf(b.w);
                *(bf16x8*)(w2b + (size_t)n * FFN + (size_t)(c ^ (n & 7)) * 8) = v;
            }
        }
        return;
    }
    if (bid < 780) {
        int k = (bid - 768) * 256 + tid;
        if (k < FFN) {
            float r[32];
#pragma unroll
            for (int w = 0; w < 10; ++w) r[w] = w1[k * 10 + w];
            r[10] = b1[k];
#pragma unroll
            for (int w = 11; w < 32; ++w) r[w] = 0.f;
#pragma unroll
            for (int c = 0; c < 4; ++c) {
                bf16x8 v;
#pragma unroll
                for (int e = 0; e < 8; ++e) v[e] = (short)f2bf(r[c * 8 + e]);
                *(bf16x8*)(w1p + (size_t)k * 32 + (size_t)((c ^ (k & 3)) * 8)) = v;
            }
        }
        return;
    }

    for (int i = tid; i < 10 * 768; i += 256) wms[i] = wm[i];
    __syncthreads();

    const int wv = tid >> 6, l = tid & 63;
    const int mbase = (bid - 780) * 16 + wv * 4;
    const float thv = (l < 10) ? th[l] : 0.f;
    const float cth = __cosf(thv);

#pragma unroll
    for (int r = 0; r < 4; ++r) {
        const int m = mbase + r;
        const float4* xp = (const float4*)(x + (size_t)m * E_DIM);
        const float4 xa = xp[l], xb = xp[64 + l], xc = xp[128 + l];
        float s[10];
#pragma unroll
        for (int w = 0; w < 10; ++w) {
            const float4* wp = (const float4*)(wms + w * E_DIM);
            const float4 wa = wp[l], wb = wp[64 + l], wc = wp[128 + l];
            float t0 = xa.x * wa.x;
            float t1 = xa.y * wa.y;
            t0 = fmaf(xa.z, wa.z, t0); t1 = fmaf(xa.w, wa.w, t1);
            t0 = fmaf(xb.x, wb.x, t0); t1 = fmaf(xb.y, wb.y, t1);
            t0 = fmaf(xb.z, wb.z, t0); t1 = fmaf(xb.w, wb.w, t1);
            t0 = fmaf(xc.x, wc.x, t0); t1 = fmaf(xc.y, wc.y, t1);
            t0 = fmaf(xc.z, wc.z, t0); t1 = fmaf(xc.w, wc.w, t1);
            s[w] = t0 + t1;
        }
#pragma unroll
        for (int w = 0; w < 10; ++w) {
            float v = s[w];
            v += __shfl_xor(v, 1);  v += __shfl_xor(v, 2);  v += __shfl_xor(v, 4);
            v += __shfl_xor(v, 8);  v += __shfl_xor(v, 16); v += __shfl_xor(v, 32);
            s[w] = v;
        }
        if (l < 32) {
            float sv = 0.f;
#pragma unroll
            for (int w = 0; w < 10; ++w) sv = (l == w) ? s[w] : sv;
            float val = (l < 10) ? (cth * __cosf(sv)) : ((l == 10) ? 1.0f : 0.f);
            qp[(size_t)m * 32 + (size_t)((((l >> 3) ^ (m & 3)) * 8) + (l & 7))] = f2bf(val);
        }
    }
}

// ---------------- kG: h-ahead (hs double-buffered), low-register --------------
// 512 blocks (128 m-tiles x 4 n-slabs), 512 threads (8 waves, 2m x 4n).
// BM=128, BN=192, BK=64. LDS = 2x24K (w2s) + 2x16K (hs) = 80 KiB -> 2 blocks/CU.
// Step t (b=t&1): [vmcnt0; B1] -> STAGE(t+1)->w2s[b^1] -> [lgkm0; B2] ->
//   HCOMP_WR: h(t+1) = relu(mfma(f=W1(t+1), aq)) -> hs[b^1] (4 MFMA + 4 ds_write_b64)
//   reload f = W1(t+2); MAINPH(b): 14 ds_read_b128 + 24 MFMA from hs[b]/w2s[b].
__global__ __launch_bounds__(512, 4) void kG(const unsigned short* __restrict__ w2b,
                                             const float* __restrict__ b2,
                                             const unsigned short* __restrict__ qp,
                                             const unsigned short* __restrict__ w1p,
                                             float* __restrict__ outp) {
    __shared__ __align__(16) unsigned short w2s[2][192 * 64];  // 48 KB, [n][k] swz8
    __shared__ __align__(16) unsigned short hs[2][128 * 64];   // 32 KB, [m][k] swz8

    const int tid = (int)threadIdx.x;
    const int wv = tid >> 6, l = tid & 63;
    const int bid = (int)blockIdx.x;
    const int x8 = bid & 7, yb = bid >> 3;          // 2 XCDs per n-slab
    const int m0 = ((x8 & 1) * 64 + yb) * 128;
    const int n0 = (x8 >> 1) * 192;

    const int rw = tid >> 3, cw = tid & 7;   // W2 staging row/chunk
    const int wr = wv >> 2, wc = wv & 3;     // main-phase wave tile (2m x 4n)

    // h-write element offsets (swapped layout): lane l holds h[hm][ki*16+(l>>4)*4..+3]
    int hwo[4];
    {
        const int hm = wv * 16 + (l & 15);
        const int kb = (l >> 4) * 4;
#pragma unroll
        for (int ki = 0; ki < 4; ++ki) {
            int k = ki * 16 + kb;
            int c = k >> 3;
            hwo[ki] = hm * 64 + ((c ^ (hm & 7)) * 8) + (k & 7);
        }
    }

    const unsigned short* p1 = w1p + (l & 15) * 32 + ((l >> 4) ^ (l & 3)) * 8;

#define STAGE(BUF, KT) do { int k0_ = (KT) * 64;                                   \
    _Pragma("unroll") for (int i_ = 0; i_ < 3; ++i_) {                             \
        int r_ = i_ * 64 + rw;                                                     \
        gload16(w2b + (size_t)(n0 + r_) * FFN + k0_ + (size_t)cw * 8,              \
                (unsigned short*)w2s[BUF] + i_ * 4096 + wv * 512); } } while (0)

#define LOADW1C(KT) do {                                                           \
    const unsigned short* pn_ = p1 + (size_t)(KT) * 2048;                          \
    f0 = *(const bf16x8*)(pn_);                                                    \
    f1 = *(const bf16x8*)(pn_ + 512);                                              \
    f2 = *(const bf16x8*)(pn_ + 1024);                                             \
    f3 = *(const bf16x8*)(pn_ + 1536);                                             \
} while (0)

    // compute h from f/aq and write straight into hs[BUF] (no persistent regs)
#define HCOMP_WR(BUF) do {                                                         \
    unsigned short* hb_ = (unsigned short*)hs[BUF];                                \
    f32x4 hv_; uint2 pw_;                                                          \
    hv_ = __builtin_amdgcn_mfma_f32_16x16x32_bf16(f0, aq, z4, 0, 0, 0);            \
    pw_.x = pkbf(fmaxf(hv_[0],0.f), fmaxf(hv_[1],0.f));                            \
    pw_.y = pkbf(fmaxf(hv_[2],0.f), fmaxf(hv_[3],0.f));                            \
    *(uint2*)(hb_ + hwo[0]) = pw_;                                                 \
    hv_ = __builtin_amdgcn_mfma_f32_16x16x32_bf16(f1, aq, z4, 0, 0, 0);            \
    pw_.x = pkbf(fmaxf(hv_[0],0.f), fmaxf(hv_[1],0.f));                            \
    pw_.y = pkbf(fmaxf(hv_[2],0.f), fmaxf(hv_[3],0.f));                            \
    *(uint2*)(hb_ + hwo[1]) = pw_;                                                 \
    hv_ = __builtin_amdgcn_mfma_f32_16x16x32_bf16(f2, aq, z4, 0, 0, 0);            \
    pw_.x = pkbf(fmaxf(hv_[0],0.f), fmaxf(hv_[1],0.f));                            \
    pw_.y = pkbf(fmaxf(hv_[2],0.f), fmaxf(hv_[3],0.f));                            \
    *(uint2*)(hb_ + hwo[2]) = pw_;                                                 \
    hv_ = __builtin_amdgcn_mfma_f32_16x16x32_bf16(f3, aq, z4, 0, 0, 0);            \
    pw_.x = pkbf(fmaxf(hv_[0],0.f), fmaxf(hv_[1],0.f));                            \
    pw_.y = pkbf(fmaxf(hv_[2],0.f), fmaxf(hv_[3],0.f));                            \
    *(uint2*)(hb_ + hwo[3]) = pw_;                                                 \
} while (0)

#define MAINPH(BUF) do {                                                           \
    const unsigned short* hb_ = (const unsigned short*)hs[BUF];                    \
    const unsigned short* w2c = (const unsigned short*)w2s[BUF];                   \
    _Pragma("unroll")                                                              \
    for (int kx = 0; kx < 2; ++kx) {                                               \
        const int kc = kx * 4 + (l >> 4);                                          \
        bf16x8 af[4], bfr[3];                                                      \
        _Pragma("unroll")                                                          \
        for (int mi = 0; mi < 4; ++mi) {                                           \
            int m_ = wr * 64 + mi * 16 + (l & 15);                                 \
            af[mi] = *(const bf16x8*)(hb_ + m_ * 64 + ((kc ^ (m_ & 7)) * 8));      \
        }                                                                          \
        _Pragma("unroll")                                                          \
        for (int ni = 0; ni < 3; ++ni) {                                           \
            int n_ = wc * 48 + ni * 16 + (l & 15);                                 \
            bfr[ni] = *(const bf16x8*)(w2c + n_ * 64 + ((kc ^ (n_ & 7)) * 8));     \
        }                                                                          \
        __builtin_amdgcn_s_setprio(1);                                             \
        _Pragma("unroll")                                                          \
        for (int ni = 0; ni < 3; ++ni)                                             \
            _Pragma("unroll")                                                      \
            for (int mi = 0; mi < 4; ++mi)                                         \
                acc[mi][ni] = __builtin_amdgcn_mfma_f32_16x16x32_bf16(             \
                    af[mi], bfr[ni], acc[mi][ni], 0, 0, 0);                        \
        __builtin_amdgcn_s_setprio(0);                                             \
    }                                                                              \
} while (0)

    // ---- prologue: aq, f=W1(0), stage(0); h(0)->hs[0]; f=W1(1) in flight ----
    bf16x8 aq = *(const bf16x8*)(qp + (size_t)(m0 + wv * 16 + (l & 15)) * 32
                                    + (size_t)(((l >> 4) ^ (l & 3)) * 8));
    bf16x8 f0, f1, f2, f3;
    const f32x4 z4 = {0.f, 0.f, 0.f, 0.f};

    STAGE(0, 0);
    LOADW1C(0);
    HCOMP_WR(0);           // compiler waits on aq/f loads itself
    LOADW1C(1);

    f32x4 acc[4][3];
#pragma unroll
    for (int a = 0; a < 4; ++a)
#pragma unroll
        for (int b = 0; b < 3; ++b) acc[a][b] = z4;

#pragma unroll 1
    for (int t = 0; t < 48; ++t) {
        const int b = t & 1;
        // B1: w2s[b] staging + f=W1(t+1) landed; all main(t-1) readers done.
        asm volatile("s_waitcnt vmcnt(0)" ::: "memory");
        __builtin_amdgcn_sched_barrier(0);
        __builtin_amdgcn_s_barrier();
        __builtin_amdgcn_sched_barrier(0);

        if (t < 47) STAGE(b ^ 1, t + 1);

        // B2: publishes hs[b] (h(t) written during main(t-1); drained here).
        asm volatile("s_waitcnt lgkmcnt(0)" ::: "memory");
        __builtin_amdgcn_sched_barrier(0);
        __builtin_amdgcn_s_barrier();
        __builtin_amdgcn_sched_barrier(0);

        if (t < 47) {
            HCOMP_WR(b ^ 1);       // h(t+1) from f=W1(t+1) -> hs[b^1]
            if (t < 46) LOADW1C(t + 2);   // WAR: after HCOMP's reads of f
        }
        MAINPH(b);
    }
#undef MAINPH
#undef HCOMP_WR
#undef LOADW1C
#undef STAGE

    // epilogue: + b2, fp32 store
#pragma unroll
    for (int ni = 0; ni < 3; ++ni) {
        int n = n0 + wc * 48 + ni * 16 + (l & 15);
        float b2v = b2[n];
#pragma unroll
        for (int mi = 0; mi < 4; ++mi) {
            int mb = m0 + wr * 64 + mi * 16 + (l >> 4) * 4;
#pragma unroll
            for (int jj = 0; jj < 4; ++jj)
                outp[(size_t)(mb + jj) * E_DIM + n] = acc[mi][ni][jj] + b2v;
        }
    }
}

extern "C" void kernel_launch(void* const* d_in, const int* in_sizes, int n_in,
                              void* d_out, int out_size, void* d_ws, size_t ws_size,
                              hipStream_t stream) {
    const float* x    = (const float*)d_in[0];
    const float* wmap = (const float*)d_in[1];
    const float* th   = (const float*)d_in[2];
    const float* w1   = (const float*)d_in[3];
    const float* b1   = (const float*)d_in[4];
    const float* w2   = (const float*)d_in[5];
    const float* b2   = (const float*)d_in[6];
    float* out = (float*)d_out;

    unsigned short* qp  = (unsigned short*)d_ws;            // 16384*32 bf16 = 1 MiB
    unsigned short* w1p = qp + (size_t)F_TOTAL * 32;        // 3072*32 bf16 = 192 KiB
    unsigned short* w2b = w1p + (size_t)FFN * 32;           // 768*3072 bf16 = 4.5 MiB

    kPre<<<1804, 256, 0, stream>>>(x, wmap, th, w1, b1, w2, w2b, w1p, qp);
    kG<<<512, 512, 0, stream>>>(w2b, b2, qp, w1p, out);
}

// Round 15
// 114.666 us; speedup vs baseline: 2.6563x; 1.0554x over previous
//
#include <hip/hip_runtime.h>
#include <hip/hip_bf16.h>

// FeedForwardQuantum: out = relu( (cos(theta)*cos(x@Wmap^T)) @ W1^T + b1 ) @ W2^T + b2
// ALL tensors fp32. Compute path: fp32 -> bf16 MFMA -> fp32 out.
//  kPre: merged pre-pass (blocks [0,768): W2->bf16 swizzled; [768,780): W1+b1 pack;
//        [780,1804): q -> qp bf16 [16384][32] swizzled).
//  kG  : r14 (h-ahead, hs+w2s both double-buffered, all VMEM compiler-visible)
//        with ONE barrier per K-step: [vmcnt(0)+lgkmcnt(0); s_barrier] then a
//        single region mixing MAINPH(b) | STAGE(t+1)->w2s[b^1] | h(t+1)->hs[b^1]
//        | W1(t+2) loads. Disjoint buffers make the single publish barrier
//        sufficient; r6's crash on this shape was asm loads (removed).

typedef __attribute__((ext_vector_type(4))) float f32x4;
typedef __attribute__((ext_vector_type(8))) short bf16x8;

#define F_TOTAL 16384
#define E_DIM   768
#define FFN     3072

static __device__ __forceinline__ unsigned short f2bf(float f) {
    union { float f; unsigned int i; } v; v.f = f;
    unsigned int r = v.i + 0x7FFFu + ((v.i >> 16) & 1u);   // RNE
    return (unsigned short)(r >> 16);
}
static __device__ __forceinline__ unsigned int pkbf(float a, float b) {
    __hip_bfloat162 h2 = __float22bfloat162_rn(float2{a, b});   // a -> low, b -> high
    union { __hip_bfloat162 h; unsigned int u; } v; v.h = h2; return v.u;
}
static __device__ __forceinline__ void gload16(const void* g, void* l) {
    __builtin_amdgcn_global_load_lds((const __attribute__((address_space(1))) unsigned int*)g,
                                     (__attribute__((address_space(3))) unsigned int*)l,
                                     16, 0, 0);
}

// ---------------- kPre: merged W2-convert / W1-pack / q-compute ---------------
__global__ __launch_bounds__(256) void kPre(const float* __restrict__ x,
                                            const float* __restrict__ wm,
                                            const float* __restrict__ th,
                                            const float* __restrict__ w1,
                                            const float* __restrict__ b1,
                                            const float* __restrict__ w2,
                                            unsigned short* __restrict__ w2b,
                                            unsigned short* __restrict__ w1p,
                                            unsigned short* __restrict__ qp) {
    __shared__ float wms[10 * 768];  // 30 KB (q role only)
    const int bid = (int)blockIdx.x;
    const int tid = (int)threadIdx.x;

    if (bid < 768) {
        const int n = bid;
#pragma unroll
        for (int c0 = 0; c0 < 2; ++c0) {
            int c = tid + c0 * 256;
            if (c < 384) {
                const float4* src = (const float4*)(w2 + (size_t)n * FFN + c * 8);
                float4 a = src[0], b = src[1];
                bf16x8 v;
                v[0] = (short)f2bf(a.x); v[1] = (short)f2bf(a.y);
                v[2] = (short)f2bf(a.z); v[3] = (short)f2bf(a.w);
                v[4] = (short)f2bf(b.x); v[5] = (short)f2bf(b.y);
                v[6] = (short)f2bf(b.z); v[7] = (short)f2bf(b.w);
                *(bf16x8*)(w2b + (size_t)n * FFN + (size_t)(c ^ (n & 7)) * 8) = v;
            }
        }
        return;
    }
    if (bid < 780) {
        int k = (bid - 768) * 256 + tid;
        if (k < FFN) {
            float r[32];
#pragma unroll
            for (int w = 0; w < 10; ++w) r[w] = w1[k * 10 + w];
            r[10] = b1[k];
#pragma unroll
            for (int w = 11; w < 32; ++w) r[w] = 0.f;
#pragma unroll
            for (int c = 0; c < 4; ++c) {
                bf16x8 v;
#pragma unroll
                for (int e = 0; e < 8; ++e) v[e] = (short)f2bf(r[c * 8 + e]);
                *(bf16x8*)(w1p + (size_t)k * 32 + (size_t)((c ^ (k & 3)) * 8)) = v;
            }
        }
        return;
    }

    for (int i = tid; i < 10 * 768; i += 256) wms[i] = wm[i];
    __syncthreads();

    const int wv = tid >> 6, l = tid & 63;
    const int mbase = (bid - 780) * 16 + wv * 4;
    const float thv = (l < 10) ? th[l] : 0.f;
    const float cth = __cosf(thv);

#pragma unroll
    for (int r = 0; r < 4; ++r) {
        const int m = mbase + r;
        const float4* xp = (const float4*)(x + (size_t)m * E_DIM);
        const float4 xa = xp[l], xb = xp[64 + l], xc = xp[128 + l];
        float s[10];
#pragma unroll
        for (int w = 0; w < 10; ++w) {
            const float4* wp = (const float4*)(wms + w * E_DIM);
            const float4 wa = wp[l], wb = wp[64 + l], wc = wp[128 + l];
            float t0 = xa.x * wa.x;
            float t1 = xa.y * wa.y;
            t0 = fmaf(xa.z, wa.z, t0); t1 = fmaf(xa.w, wa.w, t1);
            t0 = fmaf(xb.x, wb.x, t0); t1 = fmaf(xb.y, wb.y, t1);
            t0 = fmaf(xb.z, wb.z, t0); t1 = fmaf(xb.w, wb.w, t1);
            t0 = fmaf(xc.x, wc.x, t0); t1 = fmaf(xc.y, wc.y, t1);
            t0 = fmaf(xc.z, wc.z, t0); t1 = fmaf(xc.w, wc.w, t1);
            s[w] = t0 + t1;
        }
#pragma unroll
        for (int w = 0; w < 10; ++w) {
            float v = s[w];
            v += __shfl_xor(v, 1);  v += __shfl_xor(v, 2);  v += __shfl_xor(v, 4);
            v += __shfl_xor(v, 8);  v += __shfl_xor(v, 16); v += __shfl_xor(v, 32);
            s[w] = v;
        }
        if (l < 32) {
            float sv = 0.f;
#pragma unroll
            for (int w = 0; w < 10; ++w) sv = (l == w) ? s[w] : sv;
            float val = (l < 10) ? (cth * __cosf(sv)) : ((l == 10) ? 1.0f : 0.f);
            qp[(size_t)m * 32 + (size_t)((((l >> 3) ^ (m & 3)) * 8) + (l & 7))] = f2bf(val);
        }
    }
}

// ---------------- kG: 1-barrier h-ahead pipelined fused GEMM ------------------
// 512 blocks (128 m-tiles x 4 n-slabs), 512 threads (8 waves, 2m x 4n).
// BM=128, BN=192, BK=64. LDS = 2x24K (w2s) + 2x16K (hs) = 80 KiB -> 2 blocks/CU.
// Step t (b=t&1): [vmcnt(0)+lgkmcnt(0); s_barrier] -> one region:
//   STAGE(t+1)->w2s[b^1] | HCOMP_WR: h(t+1)->hs[b^1] | f=W1(t+2) | MAINPH(b).
__global__ __launch_bounds__(512, 4) void kG(const unsigned short* __restrict__ w2b,
                                             const float* __restrict__ b2,
                                             const unsigned short* __restrict__ qp,
                                             const unsigned short* __restrict__ w1p,
                                             float* __restrict__ outp) {
    __shared__ __align__(16) unsigned short w2s[2][192 * 64];  // 48 KB, [n][k] swz8
    __shared__ __align__(16) unsigned short hs[2][128 * 64];   // 32 KB, [m][k] swz8

    const int tid = (int)threadIdx.x;
    const int wv = tid >> 6, l = tid & 63;
    const int bid = (int)blockIdx.x;
    const int x8 = bid & 7, yb = bid >> 3;          // 2 XCDs per n-slab
    const int m0 = ((x8 & 1) * 64 + yb) * 128;
    const int n0 = (x8 >> 1) * 192;

    const int rw = tid >> 3, cw = tid & 7;   // W2 staging row/chunk
    const int wr = wv >> 2, wc = wv & 3;     // main-phase wave tile (2m x 4n)

    // h-write element offsets (swapped layout): lane l holds h[hm][ki*16+(l>>4)*4..+3]
    int hwo[4];
    {
        const int hm = wv * 16 + (l & 15);
        const int kb = (l >> 4) * 4;
#pragma unroll
        for (int ki = 0; ki < 4; ++ki) {
            int k = ki * 16 + kb;
            int c = k >> 3;
            hwo[ki] = hm * 64 + ((c ^ (hm & 7)) * 8) + (k & 7);
        }
    }

    const unsigned short* p1 = w1p + (l & 15) * 32 + ((l >> 4) ^ (l & 3)) * 8;

#define STAGE(BUF, KT) do { int k0_ = (KT) * 64;                                   \
    _Pragma("unroll") for (int i_ = 0; i_ < 3; ++i_) {                             \
        int r_ = i_ * 64 + rw;                                                     \
        gload16(w2b + (size_t)(n0 + r_) * FFN + k0_ + (size_t)cw * 8,              \
                (unsigned short*)w2s[BUF] + i_ * 4096 + wv * 512); } } while (0)

#define LOADW1C(KT) do {                                                           \
    const unsigned short* pn_ = p1 + (size_t)(KT) * 2048;                          \
    f0 = *(const bf16x8*)(pn_);                                                    \
    f1 = *(const bf16x8*)(pn_ + 512);                                              \
    f2 = *(const bf16x8*)(pn_ + 1024);                                             \
    f3 = *(const bf16x8*)(pn_ + 1536);                                             \
} while (0)

    // compute h from f/aq and write straight into hs[BUF]
#define HCOMP_WR(BUF) do {                                                         \
    unsigned short* hb_ = (unsigned short*)hs[BUF];                                \
    f32x4 hv_; uint2 pw_;                                                          \
    hv_ = __builtin_amdgcn_mfma_f32_16x16x32_bf16(f0, aq, z4, 0, 0, 0);            \
    pw_.x = pkbf(fmaxf(hv_[0],0.f), fmaxf(hv_[1],0.f));                            \
    pw_.y = pkbf(fmaxf(hv_[2],0.f), fmaxf(hv_[3],0.f));                            \
    *(uint2*)(hb_ + hwo[0]) = pw_;                                                 \
    hv_ = __builtin_amdgcn_mfma_f32_16x16x32_bf16(f1, aq, z4, 0, 0, 0);            \
    pw_.x = pkbf(fmaxf(hv_[0],0.f), fmaxf(hv_[1],0.f));                            \
    pw_.y = pkbf(fmaxf(hv_[2],0.f), fmaxf(hv_[3],0.f));                            \
    *(uint2*)(hb_ + hwo[1]) = pw_;                                                 \
    hv_ = __builtin_amdgcn_mfma_f32_16x16x32_bf16(f2, aq, z4, 0, 0, 0);            \
    pw_.x = pkbf(fmaxf(hv_[0],0.f), fmaxf(hv_[1],0.f));                            \
    pw_.y = pkbf(fmaxf(hv_[2],0.f), fmaxf(hv_[3],0.f));                            \
    *(uint2*)(hb_ + hwo[2]) = pw_;                                                 \
    hv_ = __builtin_amdgcn_mfma_f32_16x16x32_bf16(f3, aq, z4, 0, 0, 0);            \
    pw_.x = pkbf(fmaxf(hv_[0],0.f), fmaxf(hv_[1],0.f));                            \
    pw_.y = pkbf(fmaxf(hv_[2],0.f), fmaxf(hv_[3],0.f));                            \
    *(uint2*)(hb_ + hwo[3]) = pw_;                                                 \
} while (0)

#define MAINPH(BUF) do {                                                           \
    const unsigned short* hb_ = (const unsigned short*)hs[BUF];                    \
    const unsigned short* w2c = (const unsigned short*)w2s[BUF];                   \
    _Pragma("unroll")                                                              \
    for (int kx = 0; kx < 2; ++kx) {                                               \
        const int kc = kx * 4 + (l >> 4);                                          \
        bf16x8 af[4], bfr[3];                                                      \
        _Pragma("unroll")                                                          \
        for (int mi = 0; mi < 4; ++mi) {                                           \
            int m_ = wr * 64 + mi * 16 + (l & 15);                                 \
            af[mi] = *(const bf16x8*)(hb_ + m_ * 64 + ((kc ^ (m_ & 7)) * 8));      \
        }                                                                          \
        _Pragma("unroll")                                                          \
        for (int ni = 0; ni < 3; ++ni) {                                           \
            int n_ = wc * 48 + ni * 16 + (l & 15);                                 \
            bfr[ni] = *(const bf16x8*)(w2c + n_ * 64 + ((kc ^ (n_ & 7)) * 8));     \
        }                                                                          \
        __builtin_amdgcn_s_setprio(1);                                             \
        _Pragma("unroll")                                                          \
        for (int ni = 0; ni < 3; ++ni)                                             \
            _Pragma("unroll")                                                      \
            for (int mi = 0; mi < 4; ++mi)                                         \
                acc[mi][ni] = __builtin_amdgcn_mfma_f32_16x16x32_bf16(             \
                    af[mi], bfr[ni], acc[mi][ni], 0, 0, 0);                        \
        __builtin_amdgcn_s_setprio(0);                                             \
    }                                                                              \
} while (0)

    // ---- prologue: aq, f=W1(0), stage(0); h(0)->hs[0]; f=W1(1) in flight ----
    bf16x8 aq = *(const bf16x8*)(qp + (size_t)(m0 + wv * 16 + (l & 15)) * 32
                                    + (size_t)(((l >> 4) ^ (l & 3)) * 8));
    bf16x8 f0, f1, f2, f3;
    const f32x4 z4 = {0.f, 0.f, 0.f, 0.f};

    STAGE(0, 0);
    LOADW1C(0);
    HCOMP_WR(0);           // compiler waits on aq/f loads itself
    LOADW1C(1);

    f32x4 acc[4][3];
#pragma unroll
    for (int a = 0; a < 4; ++a)
#pragma unroll
        for (int b = 0; b < 3; ++b) acc[a][b] = z4;

#pragma unroll 1
    for (int t = 0; t < 48; ++t) {
        const int b = t & 1;
        // Single publish barrier: stage(t) + W1(t+1) landed (vmcnt), hs writes of
        // h(t) drained (lgkm); all buffers for region t are ready & published.
        asm volatile("s_waitcnt vmcnt(0) lgkmcnt(0)" ::: "memory");
        __builtin_amdgcn_sched_barrier(0);
        __builtin_amdgcn_s_barrier();
        __builtin_amdgcn_sched_barrier(0);

        if (t < 47) {
            STAGE(b ^ 1, t + 1);       // -> w2s[b^1]
            HCOMP_WR(b ^ 1);           // h(t+1) from f=W1(t+1) -> hs[b^1]
            if (t < 46) LOADW1C(t + 2);   // WAR after HCOMP's reads of f
        }
        MAINPH(b);                     // reads hs[b], w2s[b]
    }
#undef MAINPH
#undef HCOMP_WR
#undef LOADW1C
#undef STAGE

    // epilogue: + b2, fp32 store
#pragma unroll
    for (int ni = 0; ni < 3; ++ni) {
        int n = n0 + wc * 48 + ni * 16 + (l & 15);
        float b2v = b2[n];
#pragma unroll
        for (int mi = 0; mi < 4; ++mi) {
            int mb = m0 + wr * 64 + mi * 16 + (l >> 4) * 4;
#pragma unroll
            for (int jj = 0; jj < 4; ++jj)
                outp[(size_t)(mb + jj) * E_DIM + n] = acc[mi][ni][jj] + b2v;
        }
    }
}

extern "C" void kernel_launch(void* const* d_in, const int* in_sizes, int n_in,
                              void* d_out, int out_size, void* d_ws, size_t ws_size,
                              hipStream_t stream) {
    const float* x    = (const float*)d_in[0];
    const float* wmap = (const float*)d_in[1];
    const float* th   = (const float*)d_in[2];
    const float* w1   = (const float*)d_in[3];
    const float* b1   = (const float*)d_in[4];
    const float* w2   = (const float*)d_in[5];
    const float* b2   = (const float*)d_in[6];
    float* out = (float*)d_out;

    unsigned short* qp  = (unsigned short*)d_ws;            // 16384*32 bf16 = 1 MiB
    unsigned short* w1p = qp + (size_t)F_TOTAL * 32;        // 3072*32 bf16 = 192 KiB
    unsigned short* w2b = w1p + (size_t)FFN * 32;           // 768*3072 bf16 = 4.5 MiB

    kPre<<<1804, 256, 0, stream>>>(x, wmap, th, w1, b1, w2, w2b, w1p, qp);
    kG<<<512, 512, 0, stream>>>(w2b, b2, qp, w1p, out);
}